// Round 2
// baseline (273.077 us; speedup 1.0000x reference)
//
#include <hip/hip_runtime.h>
#include <math.h>

#define MAP 56
#define KST 10.0f
#define BATCH 16384
#define DIM 1024
#define HID 512
#define RPB 8      // rows per block in boxcar
#define RPW 4      // rows per wave in gemv

// ---------------------------------------------------------------------------
// Kernel 1: fold W1@W2 -> WeffT [3][1024] (TRANSPOSED for float4 gemv reads),
// and b1@W2 + b2 -> beff [3]. Grid: 1025 blocks x 64 threads.
// ---------------------------------------------------------------------------
__global__ __launch_bounds__(64) void fold_weights(
    const float* __restrict__ W1, const float* __restrict__ b1,
    const float* __restrict__ W2, const float* __restrict__ b2,
    float* __restrict__ WeffT, float* __restrict__ beff)
{
    const int d = blockIdx.x;        // 0..1023 = W1 row, 1024 = bias row
    const int lane = threadIdx.x;
    const float* row = (d < DIM) ? (W1 + (size_t)d * HID) : b1;

    float a0 = 0.f, a1 = 0.f, a2 = 0.f;
    for (int h = lane; h < HID; h += 64) {
        const float w = row[h];
        a0 += w * W2[h * 3 + 0];
        a1 += w * W2[h * 3 + 1];
        a2 += w * W2[h * 3 + 2];
    }
    #pragma unroll
    for (int off = 32; off; off >>= 1) {
        a0 += __shfl_down(a0, off, 64);
        a1 += __shfl_down(a1, off, 64);
        a2 += __shfl_down(a2, off, 64);
    }
    if (lane == 0) {
        if (d < DIM) {
            WeffT[0 * DIM + d] = a0;
            WeffT[1 * DIM + d] = a1;
            WeffT[2 * DIM + d] = a2;
        } else {
            beff[0] = a0 + b2[0];
            beff[1] = a1 + b2[1];
            beff[2] = a2 + b2[2];
        }
    }
}

// ---------------------------------------------------------------------------
// Kernel 2: t4[r] = (x[r,:] @ Weff + beff, 0). Wave handles RPW rows, W
// fragments live in registers (48 VGPRs) and are reused across rows.
// Block = 256 threads = 4 waves = 16 rows. Grid = 1024.
// ---------------------------------------------------------------------------
__global__ __launch_bounds__(256) void gemv_kernel(
    const float* __restrict__ x, const float* __restrict__ WeffT,
    const float* __restrict__ beff, float4* __restrict__ t4)
{
    const int tid  = threadIdx.x;
    const int wave = tid >> 6;
    const int lane = tid & 63;
    const int row0 = blockIdx.x * (4 * RPW) + wave * RPW;

    // W fragments: element indices d = 4*lane + 256*q + {0..3}
    float4 wf[3][4];
    #pragma unroll
    for (int q = 0; q < 4; ++q)
        #pragma unroll
        for (int c = 0; c < 3; ++c)
            wf[c][q] = *(const float4*)(WeffT + c * DIM + 4 * lane + 256 * q);

    float acc[RPW][3];
    #pragma unroll
    for (int r = 0; r < RPW; ++r) { acc[r][0] = acc[r][1] = acc[r][2] = 0.f; }

    #pragma unroll
    for (int r = 0; r < RPW; ++r) {
        const float* xr = x + (size_t)(row0 + r) * DIM;
        #pragma unroll
        for (int q = 0; q < 4; ++q) {
            const float4 xv = *(const float4*)(xr + 4 * lane + 256 * q);
            acc[r][0] += xv.x * wf[0][q].x + xv.y * wf[0][q].y + xv.z * wf[0][q].z + xv.w * wf[0][q].w;
            acc[r][1] += xv.x * wf[1][q].x + xv.y * wf[1][q].y + xv.z * wf[1][q].z + xv.w * wf[1][q].w;
            acc[r][2] += xv.x * wf[2][q].x + xv.y * wf[2][q].y + xv.z * wf[2][q].z + xv.w * wf[2][q].w;
        }
    }
    #pragma unroll
    for (int off = 32; off; off >>= 1)
        #pragma unroll
        for (int r = 0; r < RPW; ++r) {
            acc[r][0] += __shfl_down(acc[r][0], off, 64);
            acc[r][1] += __shfl_down(acc[r][1], off, 64);
            acc[r][2] += __shfl_down(acc[r][2], off, 64);
        }
    if (lane == 0) {
        const float b0 = beff[0], b1 = beff[1], b2 = beff[2];
        #pragma unroll
        for (int r = 0; r < RPW; ++r)
            t4[row0 + r] = make_float4(acc[r][0] + b0, acc[r][1] + b1, acc[r][2] + b2, 0.f);
    }
}

// ---------------------------------------------------------------------------
// Kernel 3: out[r,i,j] = Vx[i]*Vy[j] from t4[r]. RPB rows per 256-thread
// block; one barrier; then pure coalesced float4 store stream (98 KB/block).
// Grid = BATCH/RPB = 2048.
// ---------------------------------------------------------------------------
__global__ __launch_bounds__(256) void boxcar_kernel(
    const float4* __restrict__ t4, float* __restrict__ out)
{
    __shared__ float  sVx[RPB][MAP];
    __shared__ float4 sVy4[RPB][MAP / 4];

    const int tid  = threadIdx.x;
    const int base = blockIdx.x * RPB;

    // Phase 1: RPB*112 sigmoid-pair entries (Vx[56] then Vy[56] per row)
    for (int e = tid; e < RPB * 2 * MAP; e += 256) {
        const int sub = e / (2 * MAP);
        const int ent = e - sub * (2 * MAP);
        const float4 t = t4[base + sub];
        const int  isY = ent >= MAP;
        const int  i   = isY ? ent - MAP : ent;
        const float tc = isY ? t.y : t.x;
        const float u  = (float)i - tc;
        const float hh = 0.5f * t.z;
        const float p  = 1.0f / (1.0f + __expf(-KST * (u + hh)));
        const float m  = 1.0f / (1.0f + __expf(-KST * (u - hh)));
        const float v  = p - m;
        if (isY) ((float*)&sVy4[sub][0])[i] = v;
        else     sVx[sub][i] = v;
    }
    __syncthreads();

    // Phase 2: RPB*784 float4 stores, consecutive threads -> consecutive 16B
    float4* ob = (float4*)(out + (size_t)base * (MAP * MAP));
    for (int g = tid; g < RPB * (MAP * MAP / 4); g += 256) {
        const int sub = g / (MAP * MAP / 4);
        const int rem = g - sub * (MAP * MAP / 4);
        const int i   = rem / (MAP / 4);
        const int jq  = rem - i * (MAP / 4);
        const float  vx = sVx[sub][i];
        const float4 vy = sVy4[sub][jq];
        ob[g] = make_float4(vx * vy.x, vx * vy.y, vx * vy.z, vx * vy.w);
    }
}

extern "C" void kernel_launch(void* const* d_in, const int* in_sizes, int n_in,
                              void* d_out, int out_size, void* d_ws, size_t ws_size,
                              hipStream_t stream) {
    const float* x  = (const float*)d_in[0];   // [16384, 1024]
    const float* W1 = (const float*)d_in[1];   // [1024, 512]
    const float* b1 = (const float*)d_in[2];   // [512]
    const float* W2 = (const float*)d_in[3];   // [512, 3]
    const float* b2 = (const float*)d_in[4];   // [3]
    float* out = (float*)d_out;                // [16384, 56, 56]

    // ws layout: WeffT [3*1024] | beff [4] | t4 [BATCH float4] (byte 12304, 16B-aligned)
    float*  WeffT = (float*)d_ws;
    float*  beff  = WeffT + 3 * DIM;
    float4* t4    = (float4*)(beff + 4);

    fold_weights<<<DIM + 1, 64, 0, stream>>>(W1, b1, W2, b2, WeffT, beff);
    gemv_kernel<<<BATCH / (4 * RPW), 256, 0, stream>>>(x, WeffT, beff, t4);
    boxcar_kernel<<<BATCH / RPB, 256, 0, stream>>>(t4, out);
}

// Round 4
// 262.654 us; speedup vs baseline: 1.0397x; 1.0397x over previous
//
#include <hip/hip_runtime.h>
#include <math.h>

#define MAP 56
#define KST 10.0f
#define BATCH 16384
#define DIM 1024
#define HID 512
#define RPB 8      // rows per block in fused kernel (4 waves x 2 rows)

// Native clang vector type — __builtin_nontemporal_* requires this (HIP's
// float4 is a struct and is rejected).
typedef float floatx4 __attribute__((ext_vector_type(4)));

// ---------------------------------------------------------------------------
// Kernel 1: fold W1@W2 -> WeffT [3][1024] (transposed for float4 reads),
// b1@W2 + b2 -> beff [3]. Grid: 1025 blocks x 64 threads. ~3 us.
// ---------------------------------------------------------------------------
__global__ __launch_bounds__(64) void fold_weights(
    const float* __restrict__ W1, const float* __restrict__ b1,
    const float* __restrict__ W2, const float* __restrict__ b2,
    float* __restrict__ WeffT, float* __restrict__ beff)
{
    const int d = blockIdx.x;        // 0..1023 = W1 row, 1024 = bias row
    const int lane = threadIdx.x;
    const float* row = (d < DIM) ? (W1 + (size_t)d * HID) : b1;

    float a0 = 0.f, a1 = 0.f, a2 = 0.f;
    for (int h = lane; h < HID; h += 64) {
        const float w = row[h];
        a0 += w * W2[h * 3 + 0];
        a1 += w * W2[h * 3 + 1];
        a2 += w * W2[h * 3 + 2];
    }
    #pragma unroll
    for (int off = 32; off; off >>= 1) {
        a0 += __shfl_down(a0, off, 64);
        a1 += __shfl_down(a1, off, 64);
        a2 += __shfl_down(a2, off, 64);
    }
    if (lane == 0) {
        if (d < DIM) {
            WeffT[0 * DIM + d] = a0;
            WeffT[1 * DIM + d] = a1;
            WeffT[2 * DIM + d] = a2;
        } else {
            beff[0] = a0 + b2[0];
            beff[1] = a1 + b2[1];
            beff[2] = a2 + b2[2];
        }
    }
}

// ---------------------------------------------------------------------------
// Kernel 2 (fused): per block of 8 rows:
//   wave w reduces rows 2w,2w+1 in-wave: t = x[row,:] @ Weff + beff -> LDS
//   one barrier; 8x112 sigmoid-pair V entries -> LDS; barrier;
//   8x784 nontemporal float4 stores (98 KB contiguous per block).
// Grid = BATCH/RPB = 2048 blocks x 256 threads.
// ---------------------------------------------------------------------------
__global__ __launch_bounds__(256) void fused_kernel(
    const float* __restrict__ x, const float* __restrict__ WeffT,
    const float* __restrict__ beff, float* __restrict__ out)
{
    __shared__ float   sVx[RPB][MAP];
    __shared__ floatx4 sVy4[RPB][MAP / 4];
    __shared__ float   st[RPB][4];

    const int tid  = threadIdx.x;
    const int wave = tid >> 6;
    const int lane = tid & 63;
    const int base = blockIdx.x * RPB;

    // ---- Phase A: two rows per wave, in-wave reduction only ----
    const float* xr0 = x + (size_t)(base + 2 * wave + 0) * DIM + 4 * lane;
    const float* xr1 = x + (size_t)(base + 2 * wave + 1) * DIM + 4 * lane;
    float a00 = 0.f, a01 = 0.f, a02 = 0.f;   // row 0 accs
    float a10 = 0.f, a11 = 0.f, a12 = 0.f;   // row 1 accs
    #pragma unroll
    for (int q = 0; q < 4; ++q) {
        const int off = 256 * q;
        const floatx4 w0 = *(const floatx4*)(WeffT + 0 * DIM + 4 * lane + off);
        const floatx4 w1 = *(const floatx4*)(WeffT + 1 * DIM + 4 * lane + off);
        const floatx4 w2 = *(const floatx4*)(WeffT + 2 * DIM + 4 * lane + off);
        const floatx4 x0 = __builtin_nontemporal_load((const floatx4*)(xr0 + off));
        const floatx4 x1 = __builtin_nontemporal_load((const floatx4*)(xr1 + off));
        a00 += x0.x * w0.x + x0.y * w0.y + x0.z * w0.z + x0.w * w0.w;
        a01 += x0.x * w1.x + x0.y * w1.y + x0.z * w1.z + x0.w * w1.w;
        a02 += x0.x * w2.x + x0.y * w2.y + x0.z * w2.z + x0.w * w2.w;
        a10 += x1.x * w0.x + x1.y * w0.y + x1.z * w0.z + x1.w * w0.w;
        a11 += x1.x * w1.x + x1.y * w1.y + x1.z * w1.z + x1.w * w1.w;
        a12 += x1.x * w2.x + x1.y * w2.y + x1.z * w2.z + x1.w * w2.w;
    }
    #pragma unroll
    for (int off = 32; off; off >>= 1) {
        a00 += __shfl_down(a00, off, 64);
        a01 += __shfl_down(a01, off, 64);
        a02 += __shfl_down(a02, off, 64);
        a10 += __shfl_down(a10, off, 64);
        a11 += __shfl_down(a11, off, 64);
        a12 += __shfl_down(a12, off, 64);
    }
    if (lane == 0) {
        const float b0 = beff[0], b1 = beff[1], b2 = beff[2];
        st[2 * wave + 0][0] = a00 + b0;
        st[2 * wave + 0][1] = a01 + b1;
        st[2 * wave + 0][2] = a02 + b2;
        st[2 * wave + 1][0] = a10 + b0;
        st[2 * wave + 1][1] = a11 + b1;
        st[2 * wave + 1][2] = a12 + b2;
    }
    __syncthreads();

    // ---- Phase B: 8 rows x (Vx[56], Vy[56]) = 896 entries ----
    for (int e = tid; e < RPB * 2 * MAP; e += 256) {
        const int sub = e / (2 * MAP);
        const int ent = e - sub * (2 * MAP);
        const int isY = ent >= MAP;
        const int i   = isY ? ent - MAP : ent;
        const float tc = isY ? st[sub][1] : st[sub][0];
        const float u  = (float)i - tc;
        const float hh = 0.5f * st[sub][2];
        const float p  = 1.0f / (1.0f + __expf(-KST * (u + hh)));
        const float m  = 1.0f / (1.0f + __expf(-KST * (u - hh)));
        const float v  = p - m;
        if (isY) ((float*)&sVy4[sub][0])[i] = v;
        else     sVx[sub][i] = v;
    }
    __syncthreads();

    // ---- Phase C: 6272 nontemporal float4 stores, block-contiguous ----
    floatx4* ob = (floatx4*)(out + (size_t)base * (MAP * MAP));
    for (int g = tid; g < RPB * (MAP * MAP / 4); g += 256) {
        const int sub = g / (MAP * MAP / 4);
        const int rem = g - sub * (MAP * MAP / 4);
        const int i   = rem / (MAP / 4);
        const int jq  = rem - i * (MAP / 4);
        const float   vx = sVx[sub][i];
        const floatx4 vy = sVy4[sub][jq];
        floatx4 o;
        o.x = vx * vy.x; o.y = vx * vy.y; o.z = vx * vy.z; o.w = vx * vy.w;
        __builtin_nontemporal_store(o, &ob[g]);
    }
}

extern "C" void kernel_launch(void* const* d_in, const int* in_sizes, int n_in,
                              void* d_out, int out_size, void* d_ws, size_t ws_size,
                              hipStream_t stream) {
    const float* x  = (const float*)d_in[0];   // [16384, 1024]
    const float* W1 = (const float*)d_in[1];   // [1024, 512]
    const float* b1 = (const float*)d_in[2];   // [512]
    const float* W2 = (const float*)d_in[3];   // [512, 3]
    const float* b2 = (const float*)d_in[4];   // [3]
    float* out = (float*)d_out;                // [16384, 56, 56]

    float* WeffT = (float*)d_ws;               // 3*1024 floats
    float* beff  = WeffT + 3 * DIM;            // 3 floats

    fold_weights<<<DIM + 1, 64, 0, stream>>>(W1, b1, W2, b2, WeffT, beff);
    fused_kernel<<<BATCH / RPB, 256, 0, stream>>>(x, WeffT, beff, out);
}